// Round 3
// baseline (386.481 us; speedup 1.0000x reference)
//
#include <hip/hip_runtime.h>
#include <hip/hip_bf16.h>

typedef __bf16 bf16_t;
typedef __bf16 bf16x8 __attribute__((ext_vector_type(8)));
typedef __bf16 bf16x2_t __attribute__((ext_vector_type(2)));
typedef float f32x4 __attribute__((ext_vector_type(4)));
typedef int   i32x4 __attribute__((ext_vector_type(4)));

#define MFMA16(A, B, C) __builtin_amdgcn_mfma_f32_16x16x32_bf16(A, B, C, 0, 0, 0)

__device__ __forceinline__ bf16x8 cvt8(f32x4 a, f32x4 b) {
    bf16x8 r;
    r[0] = (bf16_t)a[0]; r[1] = (bf16_t)a[1]; r[2] = (bf16_t)a[2]; r[3] = (bf16_t)a[3];
    r[4] = (bf16_t)b[0]; r[5] = (bf16_t)b[1]; r[6] = (bf16_t)b[2]; r[7] = (bf16_t)b[3];
    return r;
}

__device__ __forceinline__ int pack_bf16(float lo, float hi) {
    bf16x2_t t; t[0] = (bf16_t)lo; t[1] = (bf16_t)hi;
    return __builtin_bit_cast(int, t);
}

// H=8, B=256, L=128, D=64. One block per (h,b); 512 threads = 8 waves, wave w owns
// q-rows [16w, 16w+16) -> per-lane S state is 32 floats (acc[8]), not 64.
// S computed transposed (S^T = mfma(K,Q)): lane (g,c) owns q-row 16w+c, k=16kt+4g+r.
// Softmax: in-lane over 32 vals + shfl_xor {16,32}; bias PREFETCHED to regs before QK.
// PV as out^T = mfma(V^T, P^T); P fragments via ds_bpermute (intra-wave, no extra barrier).
// Plain (cached) f32x4 stores for attn/out: NT stores cost +53MB WRITE_SIZE (round-2 data).
// __launch_bounds__(512,4): VGPR+AGPR <= 128 -> 2 blocks (16 waves) per CU.
__global__ __launch_bounds__(512, 4)
void sdpa_kernel(const float* __restrict__ q, const float* __restrict__ kmat,
                 const float* __restrict__ v, const float* __restrict__ bias,
                 float* __restrict__ out, float* __restrict__ attn)
{
    constexpr int L = 128, D = 64;
    constexpr int VS = 136;  // Vt LDS stride (XOR-granule swizzled rows)
    __shared__ __align__(16) bf16_t Vt[D * VS];   // 17408 B total LDS

    const int bh   = blockIdx.x;        // h*256 + b
    const int h    = bh >> 8;
    const int tid  = threadIdx.x;       // 0..511
    const int w    = tid >> 6;          // wave 0..7
    const int lane = tid & 63;
    const int g    = lane >> 4;         // quad 0..3
    const int c    = lane & 15;

    const float* qb = q    + (size_t)bh * (L * D);
    const float* kb = kmat + (size_t)bh * (L * D);
    const float* vb = v    + (size_t)bh * (L * D);
    const float* bb = bias + (size_t)h  * (L * L);
    float* outb  = out  + (size_t)bh * (L * D);
    float* attnb = attn + (size_t)bh * (L * L);

    // ---- 1) issue V loads (coalesced 32B/lane); do NOT wait yet
    f32x4 vreg[2][2];
#pragma unroll
    for (int it = 0; it < 2; ++it) {
        const float* p = vb + tid * 8 + it * 4096;
        vreg[it][0] = *(const f32x4*)p;
        vreg[it][1] = *(const f32x4*)(p + 4);
    }

    // ---- 2) issue Q raw loads (rows 16w+c)
    f32x4 qraw[2][2];
#pragma unroll
    for (int kk = 0; kk < 2; ++kk) {
        const float* p = qb + (16 * w + c) * D + kk * 32 + g * 8;
        qraw[kk][0] = *(const f32x4*)p;
        qraw[kk][1] = *(const f32x4*)(p + 4);
    }

    // ---- 3) issue K prefetch for kt=0,1 (depth-2 pipeline)
    f32x4 kr[2][4];
    auto issueK = [&](int kt, int slot) {
        const float* p = kb + (16 * kt + c) * D + g * 8;
        kr[slot][0] = *(const f32x4*)p;
        kr[slot][1] = *(const f32x4*)(p + 4);
        kr[slot][2] = *(const f32x4*)(p + 32);
        kr[slot][3] = *(const f32x4*)(p + 36);
    };
    issueK(0, 0);
    issueK(1, 1);

    // ---- 4) issue bias prefetch (L2-resident; hides its latency under QK)
    f32x4 breg[8];
    {
        const float* brow = bb + (16 * w + c) * L;
#pragma unroll
        for (int kt = 0; kt < 8; ++kt)
            breg[kt] = *(const f32x4*)(brow + 16 * kt + 4 * g);
    }

    // ---- 5) stage Vt (waits on V loads only; Q/K/bias stay in flight)
    // Vt element (d,k) at d*VS + ((k>>3) ^ ((d>>3)&7))*8 + (k&7)
    {
        const int pp = tid & 7, sl = tid >> 3;   // d-octet, k-row (0..63)
#pragma unroll
        for (int it = 0; it < 2; ++it) {
            const int base = (((sl >> 3) + 8 * it) ^ pp) * 8 + (sl & 7);
#pragma unroll
            for (int j = 0; j < 8; ++j)
                Vt[(8 * pp + j) * VS + base] = (bf16_t)vreg[it][j >> 2][j & 3];
        }
    }

    // ---- 6) Q fragments: B[d=32kk+8g+j][n=c] = Q[16w+c][d]
    bf16x8 qf[2];
#pragma unroll
    for (int kk = 0; kk < 2; ++kk)
        qf[kk] = cvt8(qraw[kk][0], qraw[kk][1]);

    // ---- 7) S^T = K Q^T with depth-2 K prefetch
    // acc[kt][r] = S[q=16w+c][k=16kt+4g+r]
    f32x4 acc[8];
#pragma unroll
    for (int kt = 0; kt < 8; ++kt)
        acc[kt] = f32x4{0.f, 0.f, 0.f, 0.f};
#pragma unroll
    for (int kt = 0; kt < 8; ++kt) {
        const int slot = kt & 1;
        const bf16x8 kf0 = cvt8(kr[slot][0], kr[slot][1]);
        const bf16x8 kf1 = cvt8(kr[slot][2], kr[slot][3]);
        if (kt < 6) issueK(kt + 2, slot);
        acc[kt] = MFMA16(kf0, qf[0], acc[kt]);
        acc[kt] = MFMA16(kf1, qf[1], acc[kt]);
    }

    // ---- 8) softmax (row q=16w+c lives in the 4 lanes sharing c) + attn store + pack
    int pk[8][2];   // pk[kt][hh] = bf16x2( P[q][16kt+4g+2hh], P[q][16kt+4g+2hh+1] )
    {
        float* arow = attnb + (16 * w + c) * L;

        float mkt[8];
#pragma unroll
        for (int kt = 0; kt < 8; ++kt) {
            float s0 = acc[kt][0] * 0.125f + breg[kt][0];
            float s1 = acc[kt][1] * 0.125f + breg[kt][1];
            float s2 = acc[kt][2] * 0.125f + breg[kt][2];
            float s3 = acc[kt][3] * 0.125f + breg[kt][3];
            acc[kt][0] = s0; acc[kt][1] = s1; acc[kt][2] = s2; acc[kt][3] = s3;
            mkt[kt] = fmaxf(fmaxf(s0, s1), fmaxf(s2, s3));
        }
        float m = fmaxf(fmaxf(fmaxf(mkt[0], mkt[1]), fmaxf(mkt[2], mkt[3])),
                        fmaxf(fmaxf(mkt[4], mkt[5]), fmaxf(mkt[6], mkt[7])));
        m = fmaxf(m, __shfl_xor(m, 16));
        m = fmaxf(m, __shfl_xor(m, 32));

        float skt[8];
#pragma unroll
        for (int kt = 0; kt < 8; ++kt) {
            float e0 = exp2f((acc[kt][0] - m) * 1.4426950408889634f);
            float e1 = exp2f((acc[kt][1] - m) * 1.4426950408889634f);
            float e2 = exp2f((acc[kt][2] - m) * 1.4426950408889634f);
            float e3 = exp2f((acc[kt][3] - m) * 1.4426950408889634f);
            acc[kt][0] = e0; acc[kt][1] = e1; acc[kt][2] = e2; acc[kt][3] = e3;
            skt[kt] = (e0 + e1) + (e2 + e3);
        }
        float sum = ((skt[0] + skt[1]) + (skt[2] + skt[3])) +
                    ((skt[4] + skt[5]) + (skt[6] + skt[7]));
        sum += __shfl_xor(sum, 16);
        sum += __shfl_xor(sum, 32);
        const float inv = 1.0f / sum;

#pragma unroll
        for (int kt = 0; kt < 8; ++kt) {
            f32x4 o;
            o[0] = acc[kt][0] * inv; o[1] = acc[kt][1] * inv;
            o[2] = acc[kt][2] * inv; o[3] = acc[kt][3] * inv;
            *(f32x4*)(arow + 16 * kt + 4 * g) = o;    // plain cached store (NT hurt: r2)
            pk[kt][0] = pack_bf16(o[0], o[1]);
            pk[kt][1] = pack_bf16(o[2], o[3]);
        }
    }

    __syncthreads();   // Vt writes (step 5) -> Vt reads (below)

    // ---- 9) out^T = V^T P^T : A = Vt rows (d=16dt+c), B = P fragments via ds_bpermute.
    // Fragment for kk: bf16[j] = P[c][32kk+8g+j]; source lanes c+32(g&1) (+16),
    // kt parity = g>>1 (lane>=32) selects odd-kt bpermute result.
    const int srcA = (c + 32 * (g & 1)) * 4;
    const int srcB = srcA + 64;
    const bool hi  = lane >= 32;

    f32x4 oacc[4];
#pragma unroll
    for (int dt = 0; dt < 4; ++dt)
        oacc[dt] = f32x4{0.f, 0.f, 0.f, 0.f};

#pragma unroll
    for (int kk = 0; kk < 4; ++kk) {
        const int e0 = __builtin_amdgcn_ds_bpermute(srcA, pk[2 * kk][0]);
        const int o0 = __builtin_amdgcn_ds_bpermute(srcA, pk[2 * kk + 1][0]);
        const int e1 = __builtin_amdgcn_ds_bpermute(srcA, pk[2 * kk][1]);
        const int o1 = __builtin_amdgcn_ds_bpermute(srcA, pk[2 * kk + 1][1]);
        const int e2 = __builtin_amdgcn_ds_bpermute(srcB, pk[2 * kk][0]);
        const int o2 = __builtin_amdgcn_ds_bpermute(srcB, pk[2 * kk + 1][0]);
        const int e3 = __builtin_amdgcn_ds_bpermute(srcB, pk[2 * kk][1]);
        const int o3 = __builtin_amdgcn_ds_bpermute(srcB, pk[2 * kk + 1][1]);
        i32x4 wv;
        wv[0] = hi ? o0 : e0;
        wv[1] = hi ? o1 : e1;
        wv[2] = hi ? o2 : e2;
        wv[3] = hi ? o3 : e3;
        const bf16x8 pfrag = __builtin_bit_cast(bf16x8, wv);
#pragma unroll
        for (int dt = 0; dt < 4; ++dt) {
            const int vr = 16 * dt + c;
            const bf16x8 vf =
                *(const bf16x8*)(&Vt[vr * VS + (((4 * kk + g) ^ ((vr >> 3) & 7)) * 8)]);
            oacc[dt] = MFMA16(vf, pfrag, oacc[dt]);
        }
    }

    // ---- 10) out stores: out[q=16w+c][d=16dt+4g..+3] plain f32x4
#pragma unroll
    for (int dt = 0; dt < 4; ++dt)
        *(f32x4*)(outb + (16 * w + c) * D + 16 * dt + 4 * g) = oacc[dt];
}

extern "C" void kernel_launch(void* const* d_in, const int* in_sizes, int n_in,
                              void* d_out, int out_size, void* d_ws, size_t ws_size,
                              hipStream_t stream) {
    const float* q  = (const float*)d_in[0];
    const float* k  = (const float*)d_in[1];
    const float* v  = (const float*)d_in[2];
    const float* pb = (const float*)d_in[3];
    float* out  = (float*)d_out;
    float* attn = out + (size_t)8 * 256 * 128 * 64;   // outputs concatenated: out then attn
    sdpa_kernel<<<dim3(8 * 256), dim3(512), 0, stream>>>(q, k, v, pb, out, attn);
}

// Round 4
// 348.859 us; speedup vs baseline: 1.1078x; 1.1078x over previous
//
#include <hip/hip_runtime.h>
#include <hip/hip_bf16.h>

typedef __bf16 bf16_t;
typedef __bf16 bf16x8 __attribute__((ext_vector_type(8)));
typedef float f32x4 __attribute__((ext_vector_type(4)));

#define MFMA16(A, B, C) __builtin_amdgcn_mfma_f32_16x16x32_bf16(A, B, C, 0, 0, 0)

// load 8 consecutive f32 (32B, 16B-aligned) and round to bf16x8 (RNE)
__device__ __forceinline__ bf16x8 load_cvt8(const float* __restrict__ p) {
    f32x4 a = *(const f32x4*)p;
    f32x4 b = *(const f32x4*)(p + 4);
    bf16x8 r;
    r[0] = (bf16_t)a[0]; r[1] = (bf16_t)a[1]; r[2] = (bf16_t)a[2]; r[3] = (bf16_t)a[3];
    r[4] = (bf16_t)b[0]; r[5] = (bf16_t)b[1]; r[6] = (bf16_t)b[2]; r[7] = (bf16_t)b[3];
    return r;
}

// H=8, B=256, L=128, D=64. One block per (h,b). 4 waves; wave w owns Q rows [32w,32w+32).
// fp32 global I/O; bf16 MFMA internally (QK^T and PV), fp32 softmax.
// ROUND-0 STRUCTURE (proven <121.4us; transposed-S/bpermute rewrites measured 134-156us).
// Single change vs round 0: __launch_bounds__(256,3) -> cap regs at 170 so the
// 52KB-LDS kernel can run 3 blocks/CU (3*52224=156672 <= 163840) instead of 2.
__global__ __launch_bounds__(256, 3)
void sdpa_kernel(const float* __restrict__ q, const float* __restrict__ kmat,
                 const float* __restrict__ v, const float* __restrict__ bias,
                 float* __restrict__ out, float* __restrict__ attn)
{
    constexpr int L = 128, D = 64;
    constexpr int PS = 136;  // P LDS stride (128+8): keeps b128 16B-aligned
    constexpr int VS = 136;  // Vt LDS stride
    __shared__ __align__(16) bf16_t Pl[L * PS];   // 34816 B
    __shared__ __align__(16) bf16_t Vt[D * VS];   // 17408 B (XOR-granule swizzled)

    const int bh   = blockIdx.x;        // h*256 + b
    const int h    = bh >> 8;
    const int tid  = threadIdx.x;
    const int w    = tid >> 6;          // wave 0..3
    const int lane = tid & 63;
    const int g    = lane >> 4;         // quad 0..3
    const int c    = lane & 15;

    const float* qb = q    + (size_t)bh * (L * D);
    const float* kb = kmat + (size_t)bh * (L * D);
    const float* vb = v    + (size_t)bh * (L * D);
    const float* bb = bias + (size_t)h  * (L * L);
    float* outb  = out  + (size_t)bh * (L * D);
    float* attnb = attn + (size_t)bh * (L * L);

    // ---- V -> registers, coalesced 32B/lane. thread t holds V[t/8 + 32it][(t%8)*8 .. +8)
    f32x4 vreg[4][2];
#pragma unroll
    for (int it = 0; it < 4; ++it) {
        const float* p = vb + tid * 8 + it * 2048;
        vreg[it][0] = *(const f32x4*)p;
        vreg[it][1] = *(const f32x4*)(p + 4);
    }

    // ---- Q A-fragments straight from global: A[m=c][k = kk*32 + g*8 + j], rows 32w+16rt+c
    bf16x8 qf[2][2];
#pragma unroll
    for (int rt = 0; rt < 2; ++rt)
#pragma unroll
        for (int kk = 0; kk < 2; ++kk)
            qf[rt][kk] = load_cvt8(qb + (32 * w + 16 * rt + c) * D + kk * 32 + g * 8);

    // ---- S = Q K^T (2 row-tiles x 8 col-tiles of 16x16, K=64 in 2 steps)
    f32x4 acc[2][8];
#pragma unroll
    for (int rt = 0; rt < 2; ++rt)
#pragma unroll
        for (int ct = 0; ct < 8; ++ct)
            acc[rt][ct] = f32x4{0.f, 0.f, 0.f, 0.f};

#pragma unroll
    for (int ct = 0; ct < 8; ++ct) {
        // B[k][n] = K[n][k]: lane reads K row n=16ct+c, 32B contiguous per half
        bf16x8 kf0 = load_cvt8(kb + (16 * ct + c) * D + g * 8);
        bf16x8 kf1 = load_cvt8(kb + (16 * ct + c) * D + 32 + g * 8);
        acc[0][ct] = MFMA16(qf[0][0], kf0, acc[0][ct]);
        acc[0][ct] = MFMA16(qf[0][1], kf1, acc[0][ct]);
        acc[1][ct] = MFMA16(qf[1][0], kf0, acc[1][ct]);
        acc[1][ct] = MFMA16(qf[1][1], kf1, acc[1][ct]);
    }

    // ---- stage V transposed into LDS (bf16) with XOR-granule swizzle:
    // Vt element (d,k) at d*VS + ((k>>3) ^ ((d>>3)&7))*8 + (k&7)
    {
        const int p = tid & 7, sl = tid >> 3;   // d-octet, k-row
#pragma unroll
        for (int it = 0; it < 4; ++it) {
            const int base = (((sl >> 3) + 4 * it) ^ p) * 8 + (sl & 7);
#pragma unroll
            for (int j = 0; j < 8; ++j)
                Vt[(8 * p + j) * VS + base] = (bf16_t)vreg[it][j >> 2][j & 3];
        }
    }

    // ---- softmax: row held by the 16 lanes sharing g; 8 in-lane vals + shfl_xor {1,2,4,8}
#pragma unroll
    for (int rt = 0; rt < 2; ++rt) {
#pragma unroll
        for (int r = 0; r < 4; ++r) {
            const int row = 32 * w + 16 * rt + 4 * g + r;
            float s[8], m = -1e30f;
#pragma unroll
            for (int ct = 0; ct < 8; ++ct) {
                const float bv = bb[row * L + 16 * ct + c];
                s[ct] = acc[rt][ct][r] * 0.125f + bv;   // /TEMPERATURE + pos_bias
                m = fmaxf(m, s[ct]);
            }
            m = fmaxf(m, __shfl_xor(m, 1));
            m = fmaxf(m, __shfl_xor(m, 2));
            m = fmaxf(m, __shfl_xor(m, 4));
            m = fmaxf(m, __shfl_xor(m, 8));
            float sum = 0.f;
#pragma unroll
            for (int ct = 0; ct < 8; ++ct) {
                s[ct] = exp2f((s[ct] - m) * 1.4426950408889634f);
                sum += s[ct];
            }
            sum += __shfl_xor(sum, 1);
            sum += __shfl_xor(sum, 2);
            sum += __shfl_xor(sum, 4);
            sum += __shfl_xor(sum, 8);
            const float inv = 1.0f / sum;
#pragma unroll
            for (int ct = 0; ct < 8; ++ct)
                acc[rt][ct][r] = s[ct] * inv;
        }
    }

    // ---- P -> LDS (bf16, C-layout scatter)
#pragma unroll
    for (int rt = 0; rt < 2; ++rt)
#pragma unroll
        for (int r = 0; r < 4; ++r) {
            const int row = 32 * w + 16 * rt + 4 * g + r;
#pragma unroll
            for (int ct = 0; ct < 8; ++ct)
                Pl[row * PS + 16 * ct + c] = (bf16_t)acc[rt][ct][r];
        }

    __syncthreads();

    // ---- P -> attn global as f32, coalesced float4 stores (4096 chunks of 4 elems)
#pragma unroll
    for (int i = 0; i < 16; ++i) {
        const int c4  = tid + 256 * i;
        const int row = c4 >> 5, seg = c4 & 31;
        const bf16_t* p = &Pl[row * PS + seg * 4];
        f32x4 o;
        o[0] = (float)p[0]; o[1] = (float)p[1]; o[2] = (float)p[2]; o[3] = (float)p[3];
        *(f32x4*)(attnb + row * L + seg * 4) = o;
    }

    // ---- out = P V   (2 row-tiles x 4 col-tiles, K=128 in 4 steps)
    f32x4 oacc[2][4];
#pragma unroll
    for (int rt = 0; rt < 2; ++rt)
#pragma unroll
        for (int ct = 0; ct < 4; ++ct)
            oacc[rt][ct] = f32x4{0.f, 0.f, 0.f, 0.f};

#pragma unroll
    for (int kk = 0; kk < 4; ++kk) {
        const bf16x8 pa0 = *(const bf16x8*)(&Pl[(32 * w + c) * PS + 32 * kk + 8 * g]);
        const bf16x8 pa1 = *(const bf16x8*)(&Pl[(32 * w + 16 + c) * PS + 32 * kk + 8 * g]);
#pragma unroll
        for (int ct = 0; ct < 4; ++ct) {
            const int n = 16 * ct + c;   // V column = out column
            const bf16x8 vf =
                *(const bf16x8*)(&Vt[n * VS + (((4 * kk + g) ^ ((n >> 3) & 7)) * 8)]);
            oacc[0][ct] = MFMA16(pa0, vf, oacc[0][ct]);
            oacc[1][ct] = MFMA16(pa1, vf, oacc[1][ct]);
        }
    }

    // ---- out stores (f32 scalar; 4x64B segments/instr, L2 write-combines)
#pragma unroll
    for (int rt = 0; rt < 2; ++rt)
#pragma unroll
        for (int ct = 0; ct < 4; ++ct)
#pragma unroll
            for (int r = 0; r < 4; ++r) {
                const int row = 32 * w + 16 * rt + 4 * g + r;
                outb[row * D + 16 * ct + c] = oacc[rt][ct][r];
            }
}

extern "C" void kernel_launch(void* const* d_in, const int* in_sizes, int n_in,
                              void* d_out, int out_size, void* d_ws, size_t ws_size,
                              hipStream_t stream) {
    const float* q  = (const float*)d_in[0];
    const float* k  = (const float*)d_in[1];
    const float* v  = (const float*)d_in[2];
    const float* pb = (const float*)d_in[3];
    float* out  = (float*)d_out;
    float* attn = out + (size_t)8 * 256 * 128 * 64;   // outputs concatenated: out then attn
    sdpa_kernel<<<dim3(8 * 256), dim3(256), 0, stream>>>(q, k, v, pb, out, attn);
}